// Round 17
// baseline (149.790 us; speedup 1.0000x reference)
//
#include <hip/hip_runtime.h>
#include <hip/hip_bf16.h>
#include <math.h>

#define S 4096
#define D 512
#define H 8
#define DK 64
#define WIN 128

typedef __attribute__((ext_vector_type(8))) short bf16x8;
typedef __attribute__((ext_vector_type(4))) float f32x4;

__device__ __forceinline__ unsigned short f2bf(float f) {
    __hip_bfloat16 h = __float2bfloat16(f);
    return *(unsigned short*)&h;
}
__device__ __forceinline__ float bf2f(unsigned short u) {
    unsigned int x = ((unsigned int)u) << 16;
    return __uint_as_float(x);
}

// ---------------------------------------------------------------------------
// fp32 -> bf16: x (y=0) and the 4 weight matrices (y=1..4). 8 elems/thread.
// ---------------------------------------------------------------------------
__global__ __launch_bounds__(256) void conv_bf16_kernel(
    const float* __restrict__ x,
    const float* __restrict__ wq, const float* __restrict__ wk,
    const float* __restrict__ wv, const float* __restrict__ wo,
    unsigned short* __restrict__ xb,
    unsigned short* __restrict__ wqb, unsigned short* __restrict__ wkb,
    unsigned short* __restrict__ wvb, unsigned short* __restrict__ wob)
{
    const float* src; unsigned short* dst; int n;
    switch (blockIdx.y) {
        case 0:  src = x;  dst = xb;  n = S * D; break;
        case 1:  src = wq; dst = wqb; n = D * D; break;
        case 2:  src = wk; dst = wkb; n = D * D; break;
        case 3:  src = wv; dst = wvb; n = D * D; break;
        default: src = wo; dst = wob; n = D * D; break;
    }
    const int i = (blockIdx.x * 256 + threadIdx.x) * 8;
    if (i >= n) return;
    float4 a = *(const float4*)&src[i];
    float4 b = *(const float4*)&src[i + 4];
    ushort4 o0 = {f2bf(a.x), f2bf(a.y), f2bf(a.z), f2bf(a.w)};
    ushort4 o1 = {f2bf(b.x), f2bf(b.y), f2bf(b.z), f2bf(b.w)};
    *(ushort4*)&dst[i]     = o0;
    *(ushort4*)&dst[i + 4] = o1;
}

// ---------------------------------------------------------------------------
// MFMA GEMM: C[m][n] = sum_e A[m][e]*W16[n][e] + bias[n]
// BK-split staging: two 256-wide B halves, Bs = 33.8 KB -> 4 blocks/CU.
// Outputs: C (fp32) and/or CB (bf16 row-major) and/or CBT (bf16 transposed).
// ---------------------------------------------------------------------------
__device__ __forceinline__ void mfma_gemm_body(
    const unsigned short* __restrict__ A,
    const unsigned short* __restrict__ W16,
    const float* __restrict__ bias,
    float* __restrict__ C,
    unsigned short* __restrict__ CB,
    unsigned short* __restrict__ CBT)
{
    __shared__ unsigned short Bs[64][264];   // 33.8 KB

    const int tid  = threadIdx.x;
    const int m0   = blockIdx.x * 128;
    const int n0   = blockIdx.y * 64;
    const int wv   = tid >> 6;
    const int lane = tid & 63;
    const int l16  = lane & 15;
    const int klo  = (lane >> 4) * 8;

    const unsigned short* arow0 = &A[(size_t)(m0 + wv * 32 + l16) * 512 + klo];
    const unsigned short* arow1 = arow0 + 16 * 512;

    f32x4 acc[2][4];
    #pragma unroll
    for (int r = 0; r < 2; ++r)
        #pragma unroll
        for (int nf = 0; nf < 4; ++nf)
            acc[r][nf] = (f32x4){0.f, 0.f, 0.f, 0.f};

    #pragma unroll
    for (int half = 0; half < 2; ++half) {
        const int kbase = half * 256;
        #pragma unroll
        for (int it = 0; it < 8; ++it) {
            const int c   = tid + it * 256;
            const int row = c >> 5;
            const int kc  = (c & 31) * 8;
            *(bf16x8*)&Bs[row][kc] =
                *(const bf16x8*)&W16[(size_t)(n0 + row) * 512 + kbase + kc];
        }
        __syncthreads();

        #pragma unroll 4
        for (int kb = 0; kb < 256; kb += 32) {
            bf16x8 a0 = *(const bf16x8*)&arow0[kbase + kb];
            bf16x8 a1 = *(const bf16x8*)&arow1[kbase + kb];
            #pragma unroll
            for (int nf = 0; nf < 4; ++nf) {
                bf16x8 b = *(const bf16x8*)&Bs[nf * 16 + l16][kb + klo];
                acc[0][nf] = __builtin_amdgcn_mfma_f32_16x16x32_bf16(a0, b, acc[0][nf], 0, 0, 0);
                acc[1][nf] = __builtin_amdgcn_mfma_f32_16x16x32_bf16(a1, b, acc[1][nf], 0, 0, 0);
            }
        }
        __syncthreads();
    }

    const int r0 = (lane >> 4) * 4;
    #pragma unroll
    for (int r = 0; r < 2; ++r) {
        #pragma unroll
        for (int nf = 0; nf < 4; ++nf) {
            const int col = n0 + nf * 16 + l16;
            const float bb = bias[col];
            if (CBT) {
                ushort4 o;
                o.x = f2bf(acc[r][nf][0] + bb);
                o.y = f2bf(acc[r][nf][1] + bb);
                o.z = f2bf(acc[r][nf][2] + bb);
                o.w = f2bf(acc[r][nf][3] + bb);
                const int row0 = m0 + wv * 32 + r * 16 + r0;
                *(ushort4*)&CBT[(size_t)col * 4096 + row0] = o;
            } else {
                #pragma unroll
                for (int vv = 0; vv < 4; ++vv) {
                    const int row = m0 + wv * 32 + r * 16 + r0 + vv;
                    const float val = acc[r][nf][vv] + bb;
                    if (C)  C [(size_t)row * 512 + col] = val;
                    if (CB) CB[(size_t)row * 512 + col] = f2bf(val);
                }
            }
        }
    }
}

__global__ __launch_bounds__(256) void proj3_kernel(
    const unsigned short* __restrict__ xb,
    const unsigned short* __restrict__ wqb, const float* __restrict__ bq,
    const unsigned short* __restrict__ wkb, const float* __restrict__ bk,
    const unsigned short* __restrict__ wvb, const float* __restrict__ bv,
    unsigned short* __restrict__ qb, unsigned short* __restrict__ kb,
    unsigned short* __restrict__ vT)
{
    if (blockIdx.z == 0)
        mfma_gemm_body(xb, wqb, bq, nullptr, qb, nullptr);
    else if (blockIdx.z == 1)
        mfma_gemm_body(xb, wkb, bk, nullptr, kb, nullptr);
    else
        mfma_gemm_body(xb, wvb, bv, nullptr, nullptr, vT);   // direct-transposed V
}

__global__ __launch_bounds__(256) void outproj_kernel(
    const unsigned short* __restrict__ ctxb,
    const unsigned short* __restrict__ wob, const float* __restrict__ bo,
    float* __restrict__ out)
{
    mfma_gemm_body(ctxb, wob, bo, out, nullptr, nullptr);
}

// ---------------------------------------------------------------------------
// Fused band attention with bf16 P buffer (~20 KB LDS -> 8 blocks/CU):
// MFMA QK^T (K staged to LDS, Q in registers) -> softmax (bf16 P, zeroed
// out-of-band) -> MFMA PV (A-fragment = direct b128 read of Pb; V staged
// from vT) -> ctx write -> full-row attn write. QB=16, grid (256, 8).
// Pb row stride 344 (688 B): 16B-aligned rows, bank-spread.
// ---------------------------------------------------------------------------
__global__ __launch_bounds__(256) void band_attn_kernel(
    const unsigned short* __restrict__ qb, const unsigned short* __restrict__ kb,
    const unsigned short* __restrict__ vT,
    float* __restrict__ attn, unsigned short* __restrict__ ctxb)
{
    __shared__ __align__(16) unsigned short KV[64][72];   // K:[key][d] / V:[d][s]
    __shared__ __align__(16) unsigned short Pb[16][344];  // exp-scores, bf16
    __shared__ float rinvs[16];

    const int tid = threadIdx.x;
    const int h  = blockIdx.y;
    const int q0 = blockIdx.x * 16;
    const int w0 = q0 - 128;

    const int wv   = tid >> 6;
    const int lane = tid & 63;
    const int l16  = lane & 15;
    const int klo  = (lane >> 4) * 8;
    const int r0   = (lane >> 4) * 4;

    // ---- Q fragments in registers (chunk-invariant), straight from global
    const unsigned short* qrow = &qb[(size_t)(q0 + l16) * 512 + h * 64 + klo];
    const bf16x8 aq0 = *(const bf16x8*)&qrow[0];
    const bf16x8 aq1 = *(const bf16x8*)&qrow[32];

    const int lr = tid >> 2;           // K stage: key 0..63
    const int ld = (tid & 3) * 16;     // K stage: 16 d's

    // ================= QK^T phase =================
    for (int ch = 0; ch < 5; ++ch) {
        const int c0 = w0 + ch * 64;
        if (c0 + 64 <= 0 || c0 >= S) continue;   // skip fully-outside chunks
        __syncthreads();
        {
            const int krow = min(max(c0 + lr, 0), S - 1);   // clamp partials
            const unsigned short* src = &kb[(size_t)krow * 512 + h * 64 + ld];
            *(bf16x8*)&KV[lr][ld]     = *(const bf16x8*)&src[0];
            *(bf16x8*)&KV[lr][ld + 8] = *(const bf16x8*)&src[8];
        }
        __syncthreads();

        f32x4 acc = (f32x4){0.f, 0.f, 0.f, 0.f};
        bf16x8 b0 = *(const bf16x8*)&KV[wv * 16 + l16][klo];
        bf16x8 b1 = *(const bf16x8*)&KV[wv * 16 + l16][32 + klo];
        acc = __builtin_amdgcn_mfma_f32_16x16x32_bf16(aq0, b0, acc, 0, 0, 0);
        acc = __builtin_amdgcn_mfma_f32_16x16x32_bf16(aq1, b1, acc, 0, 0, 0);
        #pragma unroll
        for (int vv = 0; vv < 4; ++vv)
            Pb[r0 + vv][ch * 64 + wv * 16 + l16] = f2bf(acc[vv] * 0.125f);
    }
    __syncthreads();

    // ---- softmax: exp in band, ZERO outside band (cols [0,320)) ----
    {
        const int r   = tid >> 4;
        const int lx  = tid & 15;
        const int i   = q0 + r;
        const int lo = max(i - WIN, 0) - w0;
        const int hi = min(i + WIN, S - 1) - w0;

        float m = -1e30f;
        for (int c = lo + lx; c <= hi; c += 16) m = fmaxf(m, bf2f(Pb[r][c]));
        m = fmaxf(m, __shfl_xor(m, 1));
        m = fmaxf(m, __shfl_xor(m, 2));
        m = fmaxf(m, __shfl_xor(m, 4));
        m = fmaxf(m, __shfl_xor(m, 8));

        float sum = 0.f;
        for (int c = lx; c < 320; c += 16) {
            unsigned short pe = 0;
            if (c >= lo && c <= hi) {
                float e = __expf(bf2f(Pb[r][c]) - m);
                sum += e;
                pe = f2bf(e);
            }
            Pb[r][c] = pe;
        }
        sum += __shfl_xor(sum, 1);
        sum += __shfl_xor(sum, 2);
        sum += __shfl_xor(sum, 4);
        sum += __shfl_xor(sum, 8);
        if (lx == 0) rinvs[r] = 1.0f / sum;
    }

    // ================= PV phase: V staged from vT; A-frag direct from Pb ===
    f32x4 pacc = (f32x4){0.f, 0.f, 0.f, 0.f};
    const int dd = tid >> 2;           // V stage: d 0..63
    const int sc = (tid & 3) * 16;     // V stage: 16 s's
    const unsigned short* vtd = &vT[((size_t)h * 64 + dd) * 4096];
    for (int ch = 0; ch < 5; ++ch) {
        const int c0 = w0 + ch * 64;
        if (c0 + 64 <= 0 || c0 >= S) continue;
        __syncthreads();
        {
            const int offs = min(max(c0 + sc, 0), S - 16);  // 16-aligned clamp; P=0 there
            *(bf16x8*)&KV[dd][sc]     = *(const bf16x8*)&vtd[offs];
            *(bf16x8*)&KV[dd][sc + 8] = *(const bf16x8*)&vtd[offs + 8];
        }
        __syncthreads();

        #pragma unroll
        for (int kk = 0; kk < 64; kk += 32) {
            bf16x8 a = *(const bf16x8*)&Pb[l16][ch * 64 + kk + klo];
            bf16x8 b = *(const bf16x8*)&KV[wv * 16 + l16][kk + klo];
            pacc = __builtin_amdgcn_mfma_f32_16x16x32_bf16(a, b, pacc, 0, 0, 0);
        }
    }

    // ---- ctx write ----
    #pragma unroll
    for (int vv = 0; vv < 4; ++vv) {
        const int row = q0 + r0 + vv;
        ctxb[(size_t)row * 512 + h * 64 + wv * 16 + l16] =
            f2bf(pacc[vv] * rinvs[r0 + vv]);
    }

    // ---- write full attn rows, coalesced; zeros outside band ----
    float* rowbase = attn + (size_t)h * S * S;
    #pragma unroll 1
    for (int r = 0; r < 16; ++r) {
        const int i = q0 + r;
        float* rowp = rowbase + (size_t)i * S;
        const int lo = max(i - WIN, 0) - w0;
        const int hi = min(i + WIN, S - 1) - w0;
        const float rv = rinvs[r];
        #pragma unroll
        for (int t = 0; t < 4; ++t) {
            const int c4 = (tid + t * 256) << 2;
            const int lc = c4 - w0;
            float4 o;
            if (lc >= lo && lc + 3 <= hi) {
                ushort4 p = *(const ushort4*)&Pb[r][lc];
                o.x = bf2f(p.x) * rv; o.y = bf2f(p.y) * rv;
                o.z = bf2f(p.z) * rv; o.w = bf2f(p.w) * rv;
            } else if (lc + 3 < lo || lc > hi) {
                o = make_float4(0.f, 0.f, 0.f, 0.f);
            } else {
                o.x = (lc + 0 >= lo && lc + 0 <= hi) ? bf2f(Pb[r][lc + 0]) * rv : 0.f;
                o.y = (lc + 1 >= lo && lc + 1 <= hi) ? bf2f(Pb[r][lc + 1]) * rv : 0.f;
                o.z = (lc + 2 >= lo && lc + 2 <= hi) ? bf2f(Pb[r][lc + 2]) * rv : 0.f;
                o.w = (lc + 3 >= lo && lc + 3 <= hi) ? bf2f(Pb[r][lc + 3]) * rv : 0.f;
            }
            *(float4*)&rowp[c4] = o;
        }
    }
}

// ---------------------------------------------------------------------------
extern "C" void kernel_launch(void* const* d_in, const int* in_sizes, int n_in,
                              void* d_out, int out_size, void* d_ws, size_t ws_size,
                              hipStream_t stream)
{
    (void)in_sizes; (void)n_in; (void)out_size; (void)ws_size;
    const float* x  = (const float*)d_in[0];
    const float* wq = (const float*)d_in[1];
    const float* bq = (const float*)d_in[2];
    const float* wk = (const float*)d_in[3];
    const float* bk = (const float*)d_in[4];
    const float* wv = (const float*)d_in[5];
    const float* bv = (const float*)d_in[6];
    const float* wo = (const float*)d_in[7];
    const float* bo = (const float*)d_in[8];

    float* out  = (float*)d_out;                       // (S, D)
    float* attn = out + (size_t)S * D;                 // (H, S, S)

    unsigned short* xb   = (unsigned short*)d_ws;      // 4 MB each
    unsigned short* qb   = xb   + (size_t)S * D;
    unsigned short* kb   = qb   + (size_t)S * D;
    unsigned short* ctxb = kb   + (size_t)S * D;
    unsigned short* vT   = ctxb + (size_t)S * D;       // 4 MB (512 x 4096)
    unsigned short* wqb  = vT   + (size_t)S * D;       // 512 KB each
    unsigned short* wkb  = wqb  + (size_t)D * D;
    unsigned short* wvb  = wkb  + (size_t)D * D;
    unsigned short* wob  = wvb  + (size_t)D * D;

    conv_bf16_kernel<<<dim3(1024, 5), 256, 0, stream>>>(
        x, wq, wk, wv, wo, xb, wqb, wkb, wvb, wob);
    proj3_kernel<<<dim3(32, 8, 3), 256, 0, stream>>>(
        xb, wqb, bq, wkb, bk, wvb, bv, qb, kb, vT);
    band_attn_kernel<<<dim3(256, 8), 256, 0, stream>>>(qb, kb, vT, attn, ctxb);
    outproj_kernel<<<dim3(32, 8), 256, 0, stream>>>(ctxb, wob, bo, out);
}

// Round 18
// 148.909 us; speedup vs baseline: 1.0059x; 1.0059x over previous
//
#include <hip/hip_runtime.h>
#include <hip/hip_bf16.h>
#include <math.h>

#define S 4096
#define D 512
#define H 8
#define DK 64
#define WIN 128

typedef __attribute__((ext_vector_type(8))) short bf16x8;
typedef __attribute__((ext_vector_type(4))) float f32x4;

__device__ __forceinline__ unsigned short f2bf(float f) {
    __hip_bfloat16 h = __float2bfloat16(f);
    return *(unsigned short*)&h;
}
__device__ __forceinline__ float bf2f(unsigned short u) {
    unsigned int x = ((unsigned int)u) << 16;
    return __uint_as_float(x);
}

// ---------------------------------------------------------------------------
// fp32 -> bf16: x (y=0) and the 4 weight matrices (y=1..4). 8 elems/thread.
// ---------------------------------------------------------------------------
__global__ __launch_bounds__(256) void conv_bf16_kernel(
    const float* __restrict__ x,
    const float* __restrict__ wq, const float* __restrict__ wk,
    const float* __restrict__ wv, const float* __restrict__ wo,
    unsigned short* __restrict__ xb,
    unsigned short* __restrict__ wqb, unsigned short* __restrict__ wkb,
    unsigned short* __restrict__ wvb, unsigned short* __restrict__ wob)
{
    const float* src; unsigned short* dst; int n;
    switch (blockIdx.y) {
        case 0:  src = x;  dst = xb;  n = S * D; break;
        case 1:  src = wq; dst = wqb; n = D * D; break;
        case 2:  src = wk; dst = wkb; n = D * D; break;
        case 3:  src = wv; dst = wvb; n = D * D; break;
        default: src = wo; dst = wob; n = D * D; break;
    }
    const int i = (blockIdx.x * 256 + threadIdx.x) * 8;
    if (i >= n) return;
    float4 a = *(const float4*)&src[i];
    float4 b = *(const float4*)&src[i + 4];
    ushort4 o0 = {f2bf(a.x), f2bf(a.y), f2bf(a.z), f2bf(a.w)};
    ushort4 o1 = {f2bf(b.x), f2bf(b.y), f2bf(b.z), f2bf(b.w)};
    *(ushort4*)&dst[i]     = o0;
    *(ushort4*)&dst[i + 4] = o1;
}

// ---------------------------------------------------------------------------
// MFMA GEMM: C[m][n] = sum_e A[m][e]*W16[n][e] + bias[n]
// BK-split staging: two 256-wide B halves, Bs = 33.8 KB -> 4 blocks/CU.
// Outputs: C (fp32) and/or CB (bf16 row-major) and/or CBT (bf16 transposed).
// ---------------------------------------------------------------------------
__device__ __forceinline__ void mfma_gemm_body(
    const unsigned short* __restrict__ A,
    const unsigned short* __restrict__ W16,
    const float* __restrict__ bias,
    float* __restrict__ C,
    unsigned short* __restrict__ CB,
    unsigned short* __restrict__ CBT)
{
    __shared__ unsigned short Bs[64][264];   // 33.8 KB

    const int tid  = threadIdx.x;
    const int m0   = blockIdx.x * 128;
    const int n0   = blockIdx.y * 64;
    const int wv   = tid >> 6;
    const int lane = tid & 63;
    const int l16  = lane & 15;
    const int klo  = (lane >> 4) * 8;

    const unsigned short* arow0 = &A[(size_t)(m0 + wv * 32 + l16) * 512 + klo];
    const unsigned short* arow1 = arow0 + 16 * 512;

    f32x4 acc[2][4];
    #pragma unroll
    for (int r = 0; r < 2; ++r)
        #pragma unroll
        for (int nf = 0; nf < 4; ++nf)
            acc[r][nf] = (f32x4){0.f, 0.f, 0.f, 0.f};

    #pragma unroll
    for (int half = 0; half < 2; ++half) {
        const int kbase = half * 256;
        #pragma unroll
        for (int it = 0; it < 8; ++it) {
            const int c   = tid + it * 256;
            const int row = c >> 5;
            const int kc  = (c & 31) * 8;
            *(bf16x8*)&Bs[row][kc] =
                *(const bf16x8*)&W16[(size_t)(n0 + row) * 512 + kbase + kc];
        }
        __syncthreads();

        #pragma unroll 4
        for (int kb = 0; kb < 256; kb += 32) {
            bf16x8 a0 = *(const bf16x8*)&arow0[kbase + kb];
            bf16x8 a1 = *(const bf16x8*)&arow1[kbase + kb];
            #pragma unroll
            for (int nf = 0; nf < 4; ++nf) {
                bf16x8 b = *(const bf16x8*)&Bs[nf * 16 + l16][kb + klo];
                acc[0][nf] = __builtin_amdgcn_mfma_f32_16x16x32_bf16(a0, b, acc[0][nf], 0, 0, 0);
                acc[1][nf] = __builtin_amdgcn_mfma_f32_16x16x32_bf16(a1, b, acc[1][nf], 0, 0, 0);
            }
        }
        __syncthreads();
    }

    const int r0 = (lane >> 4) * 4;
    #pragma unroll
    for (int r = 0; r < 2; ++r) {
        #pragma unroll
        for (int nf = 0; nf < 4; ++nf) {
            const int col = n0 + nf * 16 + l16;
            const float bb = bias[col];
            if (CBT) {
                ushort4 o;
                o.x = f2bf(acc[r][nf][0] + bb);
                o.y = f2bf(acc[r][nf][1] + bb);
                o.z = f2bf(acc[r][nf][2] + bb);
                o.w = f2bf(acc[r][nf][3] + bb);
                const int row0 = m0 + wv * 32 + r * 16 + r0;
                *(ushort4*)&CBT[(size_t)col * 4096 + row0] = o;
            } else {
                #pragma unroll
                for (int vv = 0; vv < 4; ++vv) {
                    const int row = m0 + wv * 32 + r * 16 + r0 + vv;
                    const float val = acc[r][nf][vv] + bb;
                    if (C)  C [(size_t)row * 512 + col] = val;
                    if (CB) CB[(size_t)row * 512 + col] = f2bf(val);
                }
            }
        }
    }
}

__global__ __launch_bounds__(256) void proj3_kernel(
    const unsigned short* __restrict__ xb,
    const unsigned short* __restrict__ wqb, const float* __restrict__ bq,
    const unsigned short* __restrict__ wkb, const float* __restrict__ bk,
    const unsigned short* __restrict__ wvb, const float* __restrict__ bv,
    unsigned short* __restrict__ qb, unsigned short* __restrict__ kb,
    unsigned short* __restrict__ vT)
{
    if (blockIdx.z == 0)
        mfma_gemm_body(xb, wqb, bq, nullptr, qb, nullptr);
    else if (blockIdx.z == 1)
        mfma_gemm_body(xb, wkb, bk, nullptr, kb, nullptr);
    else
        mfma_gemm_body(xb, wvb, bv, nullptr, nullptr, vT);   // direct-transposed V
}

__global__ __launch_bounds__(256) void outproj_kernel(
    const unsigned short* __restrict__ ctxb,
    const unsigned short* __restrict__ wob, const float* __restrict__ bo,
    float* __restrict__ out)
{
    mfma_gemm_body(ctxb, wob, bo, out, nullptr, nullptr);
}

// ---------------------------------------------------------------------------
// Fused band attention, wave-local staging + store/PV interleave:
// - K and V staging are wave-local (wave wv stages exactly KV rows
//   [wv*16, wv*16+16) that only it reads) -> per-wave in-order DS guarantees
//   RAW ordering -> ZERO barriers in the chunk loops (2 barriers total).
// - After softmax, attn row stores are interleaved with PV chunks; no
//   __syncthreads() ever follows a store, so the 256 KB burst drains under
//   PV compute (counted vmcnt for V loads, never a vmcnt(0)).
// bf16 P (~20 KB LDS). QB=16, grid (256, 8).
// ---------------------------------------------------------------------------
__global__ __launch_bounds__(256) void band_attn_kernel(
    const unsigned short* __restrict__ qb, const unsigned short* __restrict__ kb,
    const unsigned short* __restrict__ vT,
    float* __restrict__ attn, unsigned short* __restrict__ ctxb)
{
    __shared__ __align__(16) unsigned short KV[64][72];   // K:[key][d] / V:[d][s]
    __shared__ __align__(16) unsigned short Pb[16][344];  // exp-scores, bf16
    __shared__ float rinvs[16];

    const int tid = threadIdx.x;
    const int h  = blockIdx.y;
    const int q0 = blockIdx.x * 16;
    const int w0 = q0 - 128;

    const int wv   = tid >> 6;
    const int lane = tid & 63;
    const int l16  = lane & 15;
    const int klo  = (lane >> 4) * 8;
    const int r0   = (lane >> 4) * 4;

    // wave-local staging mapping: this lane stages KV row (wv*16 + l16s),
    // 16-element slice starting at ds0.
    const int l16s = lane & 15;
    const int ds0  = (lane >> 4) * 16;

    // ---- Q fragments in registers (chunk-invariant), straight from global
    const unsigned short* qrow = &qb[(size_t)(q0 + l16) * 512 + h * 64 + klo];
    const bf16x8 aq0 = *(const bf16x8*)&qrow[0];
    const bf16x8 aq1 = *(const bf16x8*)&qrow[32];

    // ================= QK^T phase (wave-local K staging, no barriers) ======
    for (int ch = 0; ch < 5; ++ch) {
        const int c0 = w0 + ch * 64;
        if (c0 + 64 <= 0 || c0 >= S) continue;   // skip fully-outside chunks
        {
            const int krow = min(max(c0 + wv * 16 + l16s, 0), S - 1); // clamp
            const unsigned short* src = &kb[(size_t)krow * 512 + h * 64 + ds0];
            *(bf16x8*)&KV[wv * 16 + l16s][ds0]     = *(const bf16x8*)&src[0];
            *(bf16x8*)&KV[wv * 16 + l16s][ds0 + 8] = *(const bf16x8*)&src[8];
        }
        // same-wave DS in-order: fragment reads below see the writes above
        f32x4 acc = (f32x4){0.f, 0.f, 0.f, 0.f};
        bf16x8 b0 = *(const bf16x8*)&KV[wv * 16 + l16][klo];
        bf16x8 b1 = *(const bf16x8*)&KV[wv * 16 + l16][32 + klo];
        acc = __builtin_amdgcn_mfma_f32_16x16x32_bf16(aq0, b0, acc, 0, 0, 0);
        acc = __builtin_amdgcn_mfma_f32_16x16x32_bf16(aq1, b1, acc, 0, 0, 0);
        #pragma unroll
        for (int vv = 0; vv < 4; ++vv)
            Pb[r0 + vv][ch * 64 + wv * 16 + l16] = f2bf(acc[vv] * 0.125f);
    }
    __syncthreads();                               // barrier 1 (P cross-wave)

    // ---- softmax: exp in band, ZERO outside band (cols [0,320)) ----
    {
        const int r   = tid >> 4;
        const int lx  = tid & 15;
        const int i   = q0 + r;
        const int lo = max(i - WIN, 0) - w0;
        const int hi = min(i + WIN, S - 1) - w0;

        float m = -1e30f;
        for (int c = lo + lx; c <= hi; c += 16) m = fmaxf(m, bf2f(Pb[r][c]));
        m = fmaxf(m, __shfl_xor(m, 1));
        m = fmaxf(m, __shfl_xor(m, 2));
        m = fmaxf(m, __shfl_xor(m, 4));
        m = fmaxf(m, __shfl_xor(m, 8));

        float sum = 0.f;
        for (int c = lx; c < 320; c += 16) {
            unsigned short pe = 0;
            if (c >= lo && c <= hi) {
                float e = __expf(bf2f(Pb[r][c]) - m);
                sum += e;
                pe = f2bf(e);
            }
            Pb[r][c] = pe;
        }
        sum += __shfl_xor(sum, 1);
        sum += __shfl_xor(sum, 2);
        sum += __shfl_xor(sum, 4);
        sum += __shfl_xor(sum, 8);
        if (lx == 0) rinvs[r] = 1.0f / sum;
    }
    __syncthreads();                               // barrier 2 (last)

    // ---- attn row writer (reads only Pb + rinvs; issues pure stores) ----
    float* rowbase = attn + (size_t)h * S * S;
    auto write_row = [&](int r) {
        const int i = q0 + r;
        float* rowp = rowbase + (size_t)i * S;
        const int lo = max(i - WIN, 0) - w0;
        const int hi = min(i + WIN, S - 1) - w0;
        const float rv = rinvs[r];
        #pragma unroll
        for (int t = 0; t < 4; ++t) {
            const int c4 = (tid + t * 256) << 2;
            const int lc = c4 - w0;
            float4 o;
            if (lc >= lo && lc + 3 <= hi) {
                ushort4 p = *(const ushort4*)&Pb[r][lc];
                o.x = bf2f(p.x) * rv; o.y = bf2f(p.y) * rv;
                o.z = bf2f(p.z) * rv; o.w = bf2f(p.w) * rv;
            } else if (lc + 3 < lo || lc > hi) {
                o = make_float4(0.f, 0.f, 0.f, 0.f);
            } else {
                o.x = (lc + 0 >= lo && lc + 0 <= hi) ? bf2f(Pb[r][lc + 0]) * rv : 0.f;
                o.y = (lc + 1 >= lo && lc + 1 <= hi) ? bf2f(Pb[r][lc + 1]) * rv : 0.f;
                o.z = (lc + 2 >= lo && lc + 2 <= hi) ? bf2f(Pb[r][lc + 2]) * rv : 0.f;
                o.w = (lc + 3 >= lo && lc + 3 <= hi) ? bf2f(Pb[r][lc + 3]) * rv : 0.f;
            }
            *(float4*)&rowp[c4] = o;
        }
    };

    // ====== PV phase (wave-local V staging) interleaved with attn stores ===
    f32x4 pacc = (f32x4){0.f, 0.f, 0.f, 0.f};
    const unsigned short* vtd = &vT[((size_t)h * 64 + wv * 16 + l16s) * 4096];
    int wrow = 0;
    for (int ch = 0; ch < 5; ++ch) {
        const int c0 = w0 + ch * 64;
        const bool live = (c0 + 64 > 0) && (c0 < S);
        bf16x8 v0, v1;
        if (live) {
            const int offs = min(max(c0 + ds0, 0), S - 16);  // 16-aligned; Pb=0 there
            v0 = *(const bf16x8*)&vtd[offs];
            v1 = *(const bf16x8*)&vtd[offs + 8];
        }
        // issue ~3 rows of attn stores while the V loads are in flight
        #pragma unroll 1
        for (int k2 = 0; k2 < 3 && wrow < 16; ++k2, ++wrow) write_row(wrow);
        if (live) {
            *(bf16x8*)&KV[wv * 16 + l16s][ds0]     = v0;
            *(bf16x8*)&KV[wv * 16 + l16s][ds0 + 8] = v1;
            // same-wave DS in-order: reads below see the writes above
            #pragma unroll
            for (int kk = 0; kk < 64; kk += 32) {
                bf16x8 a = *(const bf16x8*)&Pb[l16][ch * 64 + kk + klo];
                bf16x8 b = *(const bf16x8*)&KV[wv * 16 + l16][kk + klo];
                pacc = __builtin_amdgcn_mfma_f32_16x16x32_bf16(a, b, pacc, 0, 0, 0);
            }
        }
    }
    #pragma unroll 1
    while (wrow < 16) write_row(wrow++);

    // ---- ctx write ----
    #pragma unroll
    for (int vv = 0; vv < 4; ++vv) {
        const int row = q0 + r0 + vv;
        ctxb[(size_t)row * 512 + h * 64 + wv * 16 + l16] =
            f2bf(pacc[vv] * rinvs[r0 + vv]);
    }
}

// ---------------------------------------------------------------------------
extern "C" void kernel_launch(void* const* d_in, const int* in_sizes, int n_in,
                              void* d_out, int out_size, void* d_ws, size_t ws_size,
                              hipStream_t stream)
{
    (void)in_sizes; (void)n_in; (void)out_size; (void)ws_size;
    const float* x  = (const float*)d_in[0];
    const float* wq = (const float*)d_in[1];
    const float* bq = (const float*)d_in[2];
    const float* wk = (const float*)d_in[3];
    const float* bk = (const float*)d_in[4];
    const float* wv = (const float*)d_in[5];
    const float* bv = (const float*)d_in[6];
    const float* wo = (const float*)d_in[7];
    const float* bo = (const float*)d_in[8];

    float* out  = (float*)d_out;                       // (S, D)
    float* attn = out + (size_t)S * D;                 // (H, S, S)

    unsigned short* xb   = (unsigned short*)d_ws;      // 4 MB each
    unsigned short* qb   = xb   + (size_t)S * D;
    unsigned short* kb   = qb   + (size_t)S * D;
    unsigned short* ctxb = kb   + (size_t)S * D;
    unsigned short* vT   = ctxb + (size_t)S * D;       // 4 MB (512 x 4096)
    unsigned short* wqb  = vT   + (size_t)S * D;       // 512 KB each
    unsigned short* wkb  = wqb  + (size_t)D * D;
    unsigned short* wvb  = wkb  + (size_t)D * D;
    unsigned short* wob  = wvb  + (size_t)D * D;

    conv_bf16_kernel<<<dim3(1024, 5), 256, 0, stream>>>(
        x, wq, wk, wv, wo, xb, wqb, wkb, wvb, wob);
    proj3_kernel<<<dim3(32, 8, 3), 256, 0, stream>>>(
        xb, wqb, bq, wkb, bk, wvb, bv, qb, kb, vT);
    band_attn_kernel<<<dim3(256, 8), 256, 0, stream>>>(qb, kb, vT, attn, ctxb);
    outproj_kernel<<<dim3(32, 8), 256, 0, stream>>>(ctxb, wob, bo, out);
}